// Round 5
// baseline (69.348 us; speedup 1.0000x reference)
//
#include <hip/hip_runtime.h>
#include <math.h>

// Problem constants
#define HW 64
#define NB 2
#define NCIN 128
#define NCH 32

typedef float f32x4 __attribute__((ext_vector_type(4)));

// ws layout:
//   fm   : float[2*64*64]            @ 0        (32768 B)
//   offs : int4 [8192]               @ 32768    (131072 B)
//   wts  : float4[8192]              @ 163840   (131072 B)

// ---------------- kernel 1: fm = mean over 128 channels ----------------
__global__ __launch_bounds__(256) void k_mean(const float* __restrict__ feat,
                                              float* __restrict__ fm) {
    int bh = blockIdx.x;            // b*64 + h
    int w  = threadIdx.x & 63;
    int cg = threadIdx.x >> 6;      // 0..3, each sums 32 channels
    int b = bh >> 6, h = bh & 63;
    const float* base = feat + ((size_t)(b * NCIN) * 64 + h) * 64 + w;
    float s = 0.f;
    #pragma unroll
    for (int c = 0; c < 32; ++c)
        s += base[(size_t)(cg * 32 + c) * 4096];
    __shared__ float red[4][64];
    red[cg][w] = s;
    __syncthreads();
    if (cg == 0) {
        float tot = red[0][w] + red[1][w] + red[2][w] + red[3][w];
        fm[bh * 64 + w] = tot * (1.f / 128.f);
    }
}

// ------------- kernel 2: per-position offsets/weights/gain -------------
__global__ __launch_bounds__(256) void k_params(
    const float* __restrict__ fm,
    const float* __restrict__ W_in, const float* __restrict__ b_in,
    const float* __restrict__ W_dw, const float* __restrict__ b_dw,
    const float* __restrict__ W_ofs, const float* __restrict__ W_a,
    const float* __restrict__ b_a, const float* __restrict__ lam,
    int4* __restrict__ offs, float4* __restrict__ wts)
{
    __shared__ float WD[NCH * 25];
    __shared__ float Wi[NCH], Bi[NCH], Bd[NCH], Wo0[NCH], Wo1[NCH], Wa_s[NCH];
    int t = threadIdx.x;
    for (int k = t; k < NCH * 25; k += 256) WD[k] = W_dw[k];
    if (t < NCH) {
        Wi[t]  = W_in[t];  Bi[t]  = b_in[t]; Bd[t] = b_dw[t];
        Wo0[t] = W_ofs[t]; Wo1[t] = W_ofs[NCH + t];
        Wa_s[t] = W_a[t];
    }
    __syncthreads();

    int p = blockIdx.x * 256 + t;   // 0..8191
    int b = p >> 12;
    int i = (p >> 6) & 63;
    int j = p & 63;

    // 5x5 replicate-padded patch of fm
    float patch[25];
    #pragma unroll
    for (int dy = 0; dy < 5; ++dy) {
        int ry = i + dy - 2; ry = ry < 0 ? 0 : (ry > 63 ? 63 : ry);
        #pragma unroll
        for (int dx = 0; dx < 5; ++dx) {
            int rx = j + dx - 2; rx = rx < 0 ? 0 : (rx > 63 ? 63 : rx);
            patch[dy * 5 + dx] = fm[(b * 64 + ry) * 64 + rx];
        }
    }
    float fmc = patch[12];

    float a0 = 0.f, a1 = 0.f, kA = 0.f, kB = 0.f;
    for (int c = 0; c < NCH; ++c) {
        float s = 0.f, sw = 0.f;
        #pragma unroll
        for (int q = 0; q < 25; ++q) {
            float wv = WD[c * 25 + q];
            s  += patch[q] * wv;
            sw += wv;
        }
        float pre = Wi[c] * s + Bi[c] * sw + Bd[c];
        float zc = pre > 0.f ? pre : 0.f;
        a0 += zc * Wo0[c];
        a1 += zc * Wo1[c];
        kA += Wi[c] * Wa_s[c];
        kB += Bi[c] * Wa_s[c];
    }
    float ga = 1.f + lam[0] * (fmc * kA + kB + b_a[0]);

    float yy = (i + 0.5f) * (1.f / 32.f) - 1.f;
    float xx = (j + 0.5f) * (1.f / 32.f) - 1.f;
    float pos0 = fminf(fmaxf((100.f / 64.f) * tanhf(a0) + yy, -1.f), 1.f); // y
    float pos1 = fminf(fmaxf((100.f / 64.f) * tanhf(a1) + xx, -1.f), 1.f); // x
    float y = (pos0 + 1.f) * 0.5f * 63.f;
    float x = (pos1 + 1.f) * 0.5f * 63.f;
    float y0 = floorf(y), x0 = floorf(x);
    float wy1 = y - y0, wx1 = x - x0;
    float wy0 = 1.f - wy1, wx0 = 1.f - wx1;
    int y0i = (int)y0; y0i = y0i < 0 ? 0 : (y0i > 63 ? 63 : y0i);
    int x0i = (int)x0; x0i = x0i < 0 ? 0 : (x0i > 63 ? 63 : x0i);
    int y1i = y0i + 1 > 63 ? 63 : y0i + 1;
    int x1i = x0i + 1 > 63 ? 63 : x0i + 1;

    int basep = b * 16777216;
    offs[p] = make_int4(basep + (y0i * 64 + x0i) * 4096,
                        basep + (y0i * 64 + x1i) * 4096,
                        basep + (y1i * 64 + x0i) * 4096,
                        basep + (y1i * 64 + x1i) * 4096);
    wts[p] = make_float4(wy0 * wx0 * ga, wy0 * wx1 * ga,
                         wy1 * wx0 * ga, wy1 * wx1 * ga);
}

// ------------- kernel 3: gather-sample + LDS transpose + write -------------
// block = (b, i, channel-tile of 64); 256 threads
// phase1: thread (q=t&15, jg=t>>4) loads f32x4 of channels per corner;
//         ALL 16 gather loads forced in flight via compiler memory fence
// phase2: thread (jq=t&15, cg=t>>4) writes f32x4 along j, nontemporal
__global__ __launch_bounds__(256, 1) void k_sample(
    const float* __restrict__ gauss,
    const int4* __restrict__ offs, const float4* __restrict__ wts,
    float* __restrict__ out)
{
    __shared__ float lds[64 * 65];
    int bid = blockIdx.x;
    // bijective XCD swizzle: 8192 % 8 == 0
    int swz = (bid & 7) * 1024 + (bid >> 3);
    int ct = swz & 63;              // channel tile (64 channels)
    int bi = swz >> 6;              // b*64 + i
    int b = bi >> 6, i = bi & 63;
    int c0 = ct * 64;
    int t  = threadIdx.x;
    int pbase = bi * 64;

    int q  = t & 15;                // channel quad: channels 4q..4q+3
    int jg = t >> 4;                // 0..15

    // ---- hoist all offset/weight loads ----
    int4   off[4];
    float4 wt[4];
    #pragma unroll
    for (int it = 0; it < 4; ++it) {
        off[it] = offs[pbase + it * 16 + jg];
        wt[it]  = wts[pbase + it * 16 + jg];
    }

    // ---- issue all 16 gather loads; fence forces them all in flight ----
    f32x4 A[4], B[4], C[4], D[4];
    #pragma unroll
    for (int it = 0; it < 4; ++it) {
        A[it] = *((const f32x4*)(gauss + off[it].x + c0) + q);
        B[it] = *((const f32x4*)(gauss + off[it].y + c0) + q);
        C[it] = *((const f32x4*)(gauss + off[it].z + c0) + q);
        D[it] = *((const f32x4*)(gauss + off[it].w + c0) + q);
    }
    asm volatile("" ::: "memory");   // compiler fence: no sinking loads past here

    // ---- combine + LDS transpose write ----
    #pragma unroll
    for (int it = 0; it < 4; ++it) {
        int j = it * 16 + jg;
        f32x4 r = wt[it].x * A[it] + wt[it].y * B[it]
                + wt[it].z * C[it] + wt[it].w * D[it];
        int cb = 4 * q;
        lds[(cb + 0) * 65 + j] = r.x;
        lds[(cb + 1) * 65 + j] = r.y;
        lds[(cb + 2) * 65 + j] = r.z;
        lds[(cb + 3) * 65 + j] = r.w;
    }
    __syncthreads();

    // phase 2: out[b, c0+c, i, 4*jq .. 4*jq+3], nontemporal f32x4
    size_t obase = (size_t)b * 16777216 + (size_t)c0 * 4096 + (size_t)i * 64;
    int jq = t & 15;                // j quad
    int cg = t >> 4;                // 0..15
    #pragma unroll
    for (int it = 0; it < 4; ++it) {
        int c = it * 16 + cg;
        f32x4 v;
        v.x = lds[c * 65 + 4 * jq + 0];
        v.y = lds[c * 65 + 4 * jq + 1];
        v.z = lds[c * 65 + 4 * jq + 2];
        v.w = lds[c * 65 + 4 * jq + 3];
        __builtin_nontemporal_store(v, (f32x4*)(out + obase + (size_t)c * 4096 + 4 * jq));
    }
}

extern "C" void kernel_launch(void* const* d_in, const int* in_sizes, int n_in,
                              void* d_out, int out_size, void* d_ws, size_t ws_size,
                              hipStream_t stream) {
    const float* feat  = (const float*)d_in[0];
    const float* gauss = (const float*)d_in[1];
    const float* W_in  = (const float*)d_in[2];
    const float* b_in  = (const float*)d_in[3];
    const float* W_dw  = (const float*)d_in[4];
    const float* b_dw  = (const float*)d_in[5];
    const float* W_ofs = (const float*)d_in[6];
    const float* W_a   = (const float*)d_in[7];
    const float* b_a   = (const float*)d_in[8];
    const float* lam   = (const float*)d_in[9];
    float* out = (float*)d_out;

    float* fm   = (float*)d_ws;
    int4*  offs = (int4*)((char*)d_ws + 32768);
    float4* wts = (float4*)((char*)d_ws + 32768 + 131072);

    k_mean  <<<NB * HW, 256, 0, stream>>>(feat, fm);
    k_params<<<32, 256, 0, stream>>>(fm, W_in, b_in, W_dw, b_dw,
                                     W_ofs, W_a, b_a, lam, offs, wts);
    k_sample<<<NB * HW * 64, 256, 0, stream>>>(gauss, offs, wts, out);
}

// Round 6
// 61.643 us; speedup vs baseline: 1.1250x; 1.1250x over previous
//
#include <hip/hip_runtime.h>
#include <math.h>

// Problem constants
#define HW 64
#define NB 2
#define NCIN 128
#define NCH 32

typedef float f32x4 __attribute__((ext_vector_type(4)));

// ws layout:
//   fm   : float[2*64*64]            @ 0        (32768 B)
//   offs : int4 [8192]               @ 32768    (131072 B)
//   wts  : float4[8192]              @ 163840   (131072 B)

// ---------------- kernel 1: fm = mean over 128 channels ----------------
__global__ __launch_bounds__(256) void k_mean(const float* __restrict__ feat,
                                              float* __restrict__ fm) {
    int bh = blockIdx.x;            // b*64 + h
    int w  = threadIdx.x & 63;
    int cg = threadIdx.x >> 6;      // 0..3, each sums 32 channels
    int b = bh >> 6, h = bh & 63;
    const float* base = feat + ((size_t)(b * NCIN) * 64 + h) * 64 + w;
    float s = 0.f;
    #pragma unroll
    for (int c = 0; c < 32; ++c)
        s += base[(size_t)(cg * 32 + c) * 4096];
    __shared__ float red[4][64];
    red[cg][w] = s;
    __syncthreads();
    if (cg == 0) {
        float tot = red[0][w] + red[1][w] + red[2][w] + red[3][w];
        fm[bh * 64 + w] = tot * (1.f / 128.f);
    }
}

// ------------- kernel 2: per-position offsets/weights/gain -------------
__global__ __launch_bounds__(256) void k_params(
    const float* __restrict__ fm,
    const float* __restrict__ W_in, const float* __restrict__ b_in,
    const float* __restrict__ W_dw, const float* __restrict__ b_dw,
    const float* __restrict__ W_ofs, const float* __restrict__ W_a,
    const float* __restrict__ b_a, const float* __restrict__ lam,
    int4* __restrict__ offs, float4* __restrict__ wts)
{
    __shared__ float WD[NCH * 25];
    __shared__ float Wi[NCH], Bi[NCH], Bd[NCH], Wo0[NCH], Wo1[NCH], Wa_s[NCH];
    int t = threadIdx.x;
    for (int k = t; k < NCH * 25; k += 256) WD[k] = W_dw[k];
    if (t < NCH) {
        Wi[t]  = W_in[t];  Bi[t]  = b_in[t]; Bd[t] = b_dw[t];
        Wo0[t] = W_ofs[t]; Wo1[t] = W_ofs[NCH + t];
        Wa_s[t] = W_a[t];
    }
    __syncthreads();

    int p = blockIdx.x * 256 + t;   // 0..8191
    int b = p >> 12;
    int i = (p >> 6) & 63;
    int j = p & 63;

    // 5x5 replicate-padded patch of fm
    float patch[25];
    #pragma unroll
    for (int dy = 0; dy < 5; ++dy) {
        int ry = i + dy - 2; ry = ry < 0 ? 0 : (ry > 63 ? 63 : ry);
        #pragma unroll
        for (int dx = 0; dx < 5; ++dx) {
            int rx = j + dx - 2; rx = rx < 0 ? 0 : (rx > 63 ? 63 : rx);
            patch[dy * 5 + dx] = fm[(b * 64 + ry) * 64 + rx];
        }
    }
    float fmc = patch[12];

    float a0 = 0.f, a1 = 0.f, kA = 0.f, kB = 0.f;
    for (int c = 0; c < NCH; ++c) {
        float s = 0.f, sw = 0.f;
        #pragma unroll
        for (int q = 0; q < 25; ++q) {
            float wv = WD[c * 25 + q];
            s  += patch[q] * wv;
            sw += wv;
        }
        float pre = Wi[c] * s + Bi[c] * sw + Bd[c];
        float zc = pre > 0.f ? pre : 0.f;
        a0 += zc * Wo0[c];
        a1 += zc * Wo1[c];
        kA += Wi[c] * Wa_s[c];
        kB += Bi[c] * Wa_s[c];
    }
    float ga = 1.f + lam[0] * (fmc * kA + kB + b_a[0]);

    float yy = (i + 0.5f) * (1.f / 32.f) - 1.f;
    float xx = (j + 0.5f) * (1.f / 32.f) - 1.f;
    float pos0 = fminf(fmaxf((100.f / 64.f) * tanhf(a0) + yy, -1.f), 1.f); // y
    float pos1 = fminf(fmaxf((100.f / 64.f) * tanhf(a1) + xx, -1.f), 1.f); // x
    float y = (pos0 + 1.f) * 0.5f * 63.f;
    float x = (pos1 + 1.f) * 0.5f * 63.f;
    float y0 = floorf(y), x0 = floorf(x);
    float wy1 = y - y0, wx1 = x - x0;
    float wy0 = 1.f - wy1, wx0 = 1.f - wx1;
    int y0i = (int)y0; y0i = y0i < 0 ? 0 : (y0i > 63 ? 63 : y0i);
    int x0i = (int)x0; x0i = x0i < 0 ? 0 : (x0i > 63 ? 63 : x0i);
    int y1i = y0i + 1 > 63 ? 63 : y0i + 1;
    int x1i = x0i + 1 > 63 ? 63 : x0i + 1;

    int basep = b * 16777216;
    offs[p] = make_int4(basep + (y0i * 64 + x0i) * 4096,
                        basep + (y0i * 64 + x1i) * 4096,
                        basep + (y1i * 64 + x0i) * 4096,
                        basep + (y1i * 64 + x1i) * 4096);
    wts[p] = make_float4(wy0 * wx0 * ga, wy0 * wx1 * ga,
                         wy1 * wx0 * ga, wy1 * wx1 * ga);
}

// ------------- kernel 3: gather-sample, 128-channel tile -------------
// block = (b, i, channel-tile of 128); 256 threads; LDS 32 KB XOR-swizzled.
// phase1: thread (h=t&31 -> ch quad 4h, js=t>>5 -> 8 j's): per corner load is
//         512 B contiguous over 32 lanes => 2 segments per wave-instr (vs 4).
// phase2: thread (j=t&63, cq0=t>>6): b128 LDS read + 4x 256-B NT stores.
// LDS swizzle: word(j, C) = j*128 + 4*(C ^ (j&7))   (C = channel quad 0..31)
__global__ __launch_bounds__(256) void k_sample(
    const float* __restrict__ gauss,
    const int4* __restrict__ offs, const float4* __restrict__ wts,
    float* __restrict__ out)
{
    __shared__ float lds[128 * 64];  // 32 KB exact, swizzled (no pad)
    int bid = blockIdx.x;
    // bijective XCD swizzle: 4096 % 8 == 0; same-bi tiles land on one XCD
    int swz = (bid & 7) * 512 + (bid >> 3);
    int ct = swz & 31;              // channel tile (128 channels)
    int bi = swz >> 5;              // b*64 + i
    int b = bi >> 6, i = bi & 63;
    int c0 = ct * 128;
    int t  = threadIdx.x;
    int pbase = bi * 64;

    int h  = t & 31;                // channel quad: channels 4h..4h+3
    int js = t >> 5;                // 0..7

    #pragma unroll
    for (int r = 0; r < 8; ++r) {
        int j = r * 8 + js;
        int4  off = offs[pbase + j];
        float4 wt = wts[pbase + j];
        f32x4 A = *((const f32x4*)(gauss + off.x + c0) + h);
        f32x4 B = *((const f32x4*)(gauss + off.y + c0) + h);
        f32x4 C = *((const f32x4*)(gauss + off.z + c0) + h);
        f32x4 D = *((const f32x4*)(gauss + off.w + c0) + h);
        f32x4 res = wt.x * A + wt.y * B + wt.z * C + wt.w * D;
        *(f32x4*)&lds[j * 128 + 4 * (h ^ (j & 7))] = res;
    }
    __syncthreads();

    // phase 2: out[b, c0+4*cquad+q, i, j], 256-B contiguous per instr
    size_t obase = (size_t)b * 16777216 + (size_t)c0 * 4096 + (size_t)i * 64;
    int j   = t & 63;
    int cq0 = t >> 6;               // 0..3
    #pragma unroll
    for (int m = 0; m < 8; ++m) {
        int cquad = m * 4 + cq0;    // 0..31
        f32x4 v = *(const f32x4*)&lds[j * 128 + 4 * (cquad ^ (j & 7))];
        float* po = out + obase + (size_t)(4 * cquad) * 4096 + j;
        __builtin_nontemporal_store(v.x, po);
        __builtin_nontemporal_store(v.y, po + 4096);
        __builtin_nontemporal_store(v.z, po + 8192);
        __builtin_nontemporal_store(v.w, po + 12288);
    }
}

extern "C" void kernel_launch(void* const* d_in, const int* in_sizes, int n_in,
                              void* d_out, int out_size, void* d_ws, size_t ws_size,
                              hipStream_t stream) {
    const float* feat  = (const float*)d_in[0];
    const float* gauss = (const float*)d_in[1];
    const float* W_in  = (const float*)d_in[2];
    const float* b_in  = (const float*)d_in[3];
    const float* W_dw  = (const float*)d_in[4];
    const float* b_dw  = (const float*)d_in[5];
    const float* W_ofs = (const float*)d_in[6];
    const float* W_a   = (const float*)d_in[7];
    const float* b_a   = (const float*)d_in[8];
    const float* lam   = (const float*)d_in[9];
    float* out = (float*)d_out;

    float* fm   = (float*)d_ws;
    int4*  offs = (int4*)((char*)d_ws + 32768);
    float4* wts = (float4*)((char*)d_ws + 32768 + 131072);

    k_mean  <<<NB * HW, 256, 0, stream>>>(feat, fm);
    k_params<<<32, 256, 0, stream>>>(fm, W_in, b_in, W_dw, b_dw,
                                     W_ofs, W_a, b_a, lam, offs, wts);
    k_sample<<<NB * HW * 32, 256, 0, stream>>>(gauss, offs, wts, out);
}